// Round 9
// baseline (883.888 us; speedup 1.0000x reference)
//
#include <hip/hip_runtime.h>

// QuantizedLinear M=8192 K=4096 N=11008.
// Key idea this round: TILED WORKSPACE. Prepass writes Xh/Wh in exact fragment order:
//   [tile256 mt][ktile64 t][kk 0..1][F=rowblk*2+ks 0..15][lane 0..63][16B]
// where chunk F holds rows rowblk*32+(lane&31), k16 = ks*16+(lane>>5)*8 (+0..7).
// GEMM staging = contiguous 16KB block copies (gload_lds, linear, coalesced, no swizzle);
// fragment ds_reads = lane-linear b128 (base + imm offsets) -> zero bank conflicts.
// GEMM: 256x256 tile, BK=64, 8 waves 2Mx4N, mfma_f32_32x32x16_f16, r8's race-free
// 4-phase schedule (ph0->Bhi[t+1], ph1->Alo[t+2], ph2->Ahi[t+2], ph3->Blo[t+2], vmcnt(6)),
// A 3-parity + B 2-parity rings = 160KB LDS, setprio, XCD swizzle, nt C stores.

#define K_DIM 4096
#define N_DIM 11008
#define M_DIM 8192
#define NT_K 64       // K_DIM / 64
#define AB_OFF 98304  // A region: 3 parities x 32KB; B region: 2 parities x 32KB
#define TILE_BYTES 2097152  // per 256-row stripe: 64 ktiles * 32KB

typedef _Float16 f16;
typedef _Float16 f16x8 __attribute__((ext_vector_type(8)));
typedef float f32x16 __attribute__((ext_vector_type(16)));
typedef float fv4 __attribute__((ext_vector_type(4)));
typedef int iv4 __attribute__((ext_vector_type(4)));

__device__ __forceinline__ void gload16(const void* g, void* lds) {
  __builtin_amdgcn_global_load_lds(
      (__attribute__((address_space(1))) void*)g,
      (__attribute__((address_space(3))) void*)lds,
      16, 0, 0);
}

// fused prepass into tiled layout. Thread i writes 16B (8 f16) at flat position i.
// Decompose i: [5:0]=lane, [9:6]=F, [10]=kk, [16:11]=t, [..:17]=stripe (mt or nt).
// row = stripe*256 + (F>>1)*32 + (lane&31); k = t*64 + kk*32 + (F&1)*16 + (lane>>5)*8.
__global__ __launch_bounds__(256) void prep_kernel(const float* __restrict__ x,
                                                   f16* __restrict__ xo, int n16x,
                                                   const int* __restrict__ q,
                                                   const float* __restrict__ amax,
                                                   f16* __restrict__ wo, int n16w) {
  int i = blockIdx.x * blockDim.x + threadIdx.x;
  if (i < n16x) {
    const int lam = i & 63;
    const int F = (i >> 6) & 15;
    const int kk = (i >> 10) & 1;
    const int t = (i >> 11) & 63;
    const int mt = i >> 17;
    const int row = mt * 256 + ((F >> 1) << 5) + (lam & 31);
    const int kc = t * 64 + (kk << 5) + ((F & 1) << 4) + ((lam >> 5) << 3);
    const fv4* src = (const fv4*)(x + (size_t)row * K_DIM + kc);
    fv4 a = __builtin_nontemporal_load(src);
    fv4 b = __builtin_nontemporal_load(src + 1);
    f16x8 o;
    o[0] = (f16)a.x; o[1] = (f16)a.y; o[2] = (f16)a.z; o[3] = (f16)a.w;
    o[4] = (f16)b.x; o[5] = (f16)b.y; o[6] = (f16)b.z; o[7] = (f16)b.w;
    *(f16x8*)(xo + (size_t)i * 8) = o;
  } else {
    int j = i - n16x;
    if (j >= n16w) return;
    const int lam = j & 63;
    const int F = (j >> 6) & 15;
    const int kk = (j >> 10) & 1;
    const int t = (j >> 11) & 63;
    const int nt = j >> 17;
    const int row = nt * 256 + ((F >> 1) << 5) + (lam & 31);
    const int kc = t * 64 + (kk << 5) + ((F & 1) << 4) + ((lam >> 5) << 3);
    const size_t base = (size_t)row * K_DIM + kc;
    const iv4* src = (const iv4*)(q + base);
    iv4 a = __builtin_nontemporal_load(src);
    iv4 b = __builtin_nontemporal_load(src + 1);
    float s = amax[base >> 6] * (1.0f / 7.0f);
    f16x8 o;
    o[0] = (f16)((float)a.x * s); o[1] = (f16)((float)a.y * s);
    o[2] = (f16)((float)a.z * s); o[3] = (f16)((float)a.w * s);
    o[4] = (f16)((float)b.x * s); o[5] = (f16)((float)b.y * s);
    o[6] = (f16)((float)b.z * s); o[7] = (f16)((float)b.w * s);
    *(f16x8*)(wo + (size_t)j * 8) = o;
  }
}

// LDS half-slots of 16KB (flat chunk order, identical to global tiled layout):
// A(parity ap in {0,32768,65536}, kk) @ ap + kk*16384; B(parity p, kk) @ AB_OFF + p*32768 + kk*16384.
__global__ __launch_bounds__(512, 2) void gemm_f16_bt(const f16* __restrict__ A,
                                                      const f16* __restrict__ B,
                                                      const float* __restrict__ bias,
                                                      float* __restrict__ C) {
  __shared__ __align__(16) char lds[163840];

  const int tid = threadIdx.x;
  const int w = tid >> 6;
  const int l = tid & 63;
  const int wr = w >> 2;  // 0..1 : 128 M-rows each
  const int wc = w & 3;   // 0..3 : 64 N-cols each

  // bijective XCD swizzle: nwg = 1376 = 8 * 172
  const int wg = blockIdx.x;
  const int swz = (wg & 7) * 172 + (wg >> 3);
  const int mt = swz / 43;
  const int nt = swz % 43;
  const int m0 = mt * 256;
  const int n0 = nt * 256;

  // staging sources: contiguous tiled blocks; wave w covers chunks w and w+8
  const char* Abase = (const char*)A + (size_t)mt * TILE_BYTES + (w << 10) + (l << 4);
  const char* Bbase = (const char*)B + (size_t)nt * TILE_BYTES + (w << 10) + (l << 4);

  char* ldsc = (char*)lds;

#define STAGE_A(dst_off, koff)               \
  {                                          \
    char* d_ = ldsc + (dst_off) + (w << 10); \
    gload16(Abase + (koff), d_);             \
    gload16(Abase + (koff) + 8192, d_ + 8192); \
  }
#define STAGE_B(dst_off, koff)               \
  {                                          \
    char* d_ = ldsc + (dst_off) + (w << 10); \
    gload16(Bbase + (koff), d_);             \
    gload16(Bbase + (koff) + 8192, d_ + 8192); \
  }

  f32x16 acc[4][2];
#pragma unroll
  for (int i = 0; i < 4; ++i)
#pragma unroll
    for (int j = 0; j < 2; ++j) acc[i][j] = (f32x16)0.f;

  const int l16 = l << 4;
  const int aF0 = (wr << 3) << 10;  // first A chunk byte offset: (wr*4)*2*1024
  const int bF0 = (wc << 2) << 10;  // first B chunk byte offset: (wc*2)*2*1024

  // prologue: Alo0,Ahi0,Blo0,Bhi0,Alo1,Ahi1,Blo1 = 14 loads; vmcnt(6) confirms tile 0.
  STAGE_A(0, 0);
  STAGE_A(16384, 16384);
  STAGE_B(AB_OFF, 0);
  STAGE_B(AB_OFF + 16384, 16384);
  STAGE_A(32768, 32768);
  STAGE_A(32768 + 16384, 32768 + 16384);
  STAGE_B(AB_OFF + 32768, 32768);
  asm volatile("s_waitcnt vmcnt(6)" ::: "memory");
  __builtin_amdgcn_s_barrier();

  int ap = 0;       // A parity base of tile t
  int ap2 = 65536;  // A parity base of tile t+2

  for (int t = 0; t < NT_K; ++t) {
    const int p = t & 1;
    const int pn = p ^ 1;
    const int Bb = AB_OFF + p * 32768;
    const int Bn = AB_OFF + pn * 32768;
    const int t1 = (t + 1 < NT_K) ? (t + 1) : (NT_K - 1);
    const int t2 = (t + 2 < NT_K) ? (t + 2) : (NT_K - 1);
    const int k1 = t1 * 32768;
    const int k2 = t2 * 32768;

#pragma unroll
    for (int pi = 0; pi < 4; ++pi) {
      const int kk = pi >> 1;
      const int ks = pi & 1;

      // lane-linear fragment reads: chunk F = rowblk*2 + ks, each a contiguous 1KB block
      f16x8 af[4], bf[2];
#pragma unroll
      for (int mf = 0; mf < 4; ++mf)
        af[mf] = *(const f16x8*)(ldsc + ap + kk * 16384 + aF0 + ((mf << 1) | ks) * 1024 + l16);
#pragma unroll
      for (int nf = 0; nf < 2; ++nf)
        bf[nf] = *(const f16x8*)(ldsc + Bb + kk * 16384 + bF0 + ((nf << 1) | ks) * 1024 + l16);

      if (pi == 0) {
        STAGE_B(Bn + 16384, k1 + 16384);  // Bhi[t+1] -> parity pn (untouched by tile t)
      } else if (pi == 1) {
        STAGE_A(ap2, k2);                 // Alo[t+2] -> free A parity
      } else if (pi == 2) {
        STAGE_A(ap2 + 16384, k2 + 16384); // Ahi[t+2]
      } else {
        STAGE_B(Bb, k2);                  // Blo[t+2] -> B[p][kk0], last read in ph1
      }

      __builtin_amdgcn_s_barrier();
      asm volatile("s_waitcnt lgkmcnt(0)" ::: "memory");  // dense read burst fully landed
      __builtin_amdgcn_sched_barrier(0);                  // rule #18: pin MFMA below the wait
      __builtin_amdgcn_s_setprio(1);
#pragma unroll
      for (int mf = 0; mf < 4; ++mf)
#pragma unroll
        for (int nf = 0; nf < 2; ++nf)
          acc[mf][nf] = __builtin_amdgcn_mfma_f32_32x32x16_f16(af[mf], bf[nf], acc[mf][nf], 0, 0, 0);
      __builtin_amdgcn_s_setprio(0);
      if (pi == 3) asm volatile("s_waitcnt vmcnt(6)" ::: "memory");  // confirms tile t+1
      __builtin_amdgcn_s_barrier();
    }

    ap += 32768;  if (ap == AB_OFF) ap = 0;
    ap2 += 32768; if (ap2 == AB_OFF) ap2 = 0;
  }

  // epilogue: 32x32 C/D layout col = lane&31, row = (reg&3) + 8*(reg>>2) + 4*(lane>>5)
  const int l31 = l & 31;
  const int rbase = 4 * (l >> 5);
  float bv[2];
#pragma unroll
  for (int nf = 0; nf < 2; ++nf) bv[nf] = bias[n0 + wc * 64 + nf * 32 + l31];
#pragma unroll
  for (int mf = 0; mf < 4; ++mf) {
#pragma unroll
    for (int nf = 0; nf < 2; ++nf) {
      const size_t col = n0 + wc * 64 + nf * 32 + l31;
#pragma unroll
      for (int qd = 0; qd < 4; ++qd) {
#pragma unroll
        for (int j = 0; j < 4; ++j) {
          const int row = m0 + wr * 128 + mf * 32 + rbase + 8 * qd + j;
          __builtin_nontemporal_store(acc[mf][nf][qd * 4 + j] + bv[nf],
                                      &C[(size_t)row * N_DIM + col]);
        }
      }
    }
  }
#undef STAGE_A
#undef STAGE_B
}

extern "C" void kernel_launch(void* const* d_in, const int* in_sizes, int n_in,
                              void* d_out, int out_size, void* d_ws, size_t ws_size,
                              hipStream_t stream) {
  const float* x = (const float*)d_in[0];
  const int* wq = (const int*)d_in[1];
  const float* amax = (const float*)d_in[2];
  const float* bias = (const float*)d_in[3];
  float* out = (float*)d_out;

  f16* Xh = (f16*)d_ws;                                       // 64 MB, tiled
  f16* Wh = (f16*)((char*)d_ws + (size_t)M_DIM * K_DIM * 2);  // 90.25 MB, tiled

  {
    int n16x = M_DIM * K_DIM / 8;  // 4,194,304 16B-positions (multiple of 256)
    int n16w = N_DIM * K_DIM / 8;  // 5,636,096
    int nthr = n16x + n16w;
    prep_kernel<<<(nthr + 255) / 256, 256, 0, stream>>>(x, Xh, n16x, wq, amax, Wh, n16w);
  }
  {
    dim3 grid((M_DIM / 256) * (N_DIM / 256));  // 32*43 = 1376
    gemm_f16_bt<<<grid, 512, 0, stream>>>(Xh, Wh, bias, out);
  }
}

// Round 10
// 874.813 us; speedup vs baseline: 1.0104x; 1.0104x over previous
//
#include <hip/hip_runtime.h>

// QuantizedLinear M=8192 K=4096 N=11008.
// r9 tiled workspace (lane-linear LDS reads, 0 conflicts) + software-pipelined phases:
// phase q reads frags for q+1 (ping-pong reg buffers) then MFMAs q -> compiler emits
// COUNTED lgkmcnt(6), LDS-read service overlaps matrix pipe. Only 2 barriers/K-tile
// (mid after ph1, boundary after vmcnt(6)). A 3-parity + B 2-parity rings, 160KB LDS.
// Stage plan per tile t (race-free): ph0->Bhi[t+1], ph1->Alo[t+2], ph2->Ahi[t+2], ph3->Blo[t+2].

#define K_DIM 4096
#define N_DIM 11008
#define M_DIM 8192
#define NT_K 64       // K_DIM / 64
#define AB_OFF 98304  // A region: 3 parities x 32KB; B region: 2 parities x 32KB
#define TILE_BYTES 2097152  // per 256-row stripe: 64 ktiles * 32KB

typedef _Float16 f16;
typedef _Float16 f16x8 __attribute__((ext_vector_type(8)));
typedef float f32x16 __attribute__((ext_vector_type(16)));
typedef float fv4 __attribute__((ext_vector_type(4)));
typedef int iv4 __attribute__((ext_vector_type(4)));

__device__ __forceinline__ void gload16(const void* g, void* lds) {
  __builtin_amdgcn_global_load_lds(
      (__attribute__((address_space(1))) void*)g,
      (__attribute__((address_space(3))) void*)lds,
      16, 0, 0);
}

// fused prepass into tiled layout (unchanged from r9, passed).
__global__ __launch_bounds__(256) void prep_kernel(const float* __restrict__ x,
                                                   f16* __restrict__ xo, int n16x,
                                                   const int* __restrict__ q,
                                                   const float* __restrict__ amax,
                                                   f16* __restrict__ wo, int n16w) {
  int i = blockIdx.x * blockDim.x + threadIdx.x;
  if (i < n16x) {
    const int lam = i & 63;
    const int F = (i >> 6) & 15;
    const int kk = (i >> 10) & 1;
    const int t = (i >> 11) & 63;
    const int mt = i >> 17;
    const int row = mt * 256 + ((F >> 1) << 5) + (lam & 31);
    const int kc = t * 64 + (kk << 5) + ((F & 1) << 4) + ((lam >> 5) << 3);
    const fv4* src = (const fv4*)(x + (size_t)row * K_DIM + kc);
    fv4 a = __builtin_nontemporal_load(src);
    fv4 b = __builtin_nontemporal_load(src + 1);
    f16x8 o;
    o[0] = (f16)a.x; o[1] = (f16)a.y; o[2] = (f16)a.z; o[3] = (f16)a.w;
    o[4] = (f16)b.x; o[5] = (f16)b.y; o[6] = (f16)b.z; o[7] = (f16)b.w;
    *(f16x8*)(xo + (size_t)i * 8) = o;
  } else {
    int j = i - n16x;
    if (j >= n16w) return;
    const int lam = j & 63;
    const int F = (j >> 6) & 15;
    const int kk = (j >> 10) & 1;
    const int t = (j >> 11) & 63;
    const int nt = j >> 17;
    const int row = nt * 256 + ((F >> 1) << 5) + (lam & 31);
    const int kc = t * 64 + (kk << 5) + ((F & 1) << 4) + ((lam >> 5) << 3);
    const size_t base = (size_t)row * K_DIM + kc;
    const iv4* src = (const iv4*)(q + base);
    iv4 a = __builtin_nontemporal_load(src);
    iv4 b = __builtin_nontemporal_load(src + 1);
    float s = amax[base >> 6] * (1.0f / 7.0f);
    f16x8 o;
    o[0] = (f16)((float)a.x * s); o[1] = (f16)((float)a.y * s);
    o[2] = (f16)((float)a.z * s); o[3] = (f16)((float)a.w * s);
    o[4] = (f16)((float)b.x * s); o[5] = (f16)((float)b.y * s);
    o[6] = (f16)((float)b.z * s); o[7] = (f16)((float)b.w * s);
    *(f16x8*)(wo + (size_t)j * 8) = o;
  }
}

__device__ __forceinline__ void read_frags(const char* ldsc, int abase, int bbase, int kk, int ks,
                                           int aF0, int bF0, int l16,
                                           f16x8 (&af)[4], f16x8 (&bf)[2]) {
#pragma unroll
  for (int mf = 0; mf < 4; ++mf)
    af[mf] = *(const f16x8*)(ldsc + abase + kk * 16384 + aF0 + (((mf << 1) | ks) << 10) + l16);
#pragma unroll
  for (int nf = 0; nf < 2; ++nf)
    bf[nf] = *(const f16x8*)(ldsc + bbase + kk * 16384 + bF0 + (((nf << 1) | ks) << 10) + l16);
}

__device__ __forceinline__ void mfma8(const f16x8 (&af)[4], const f16x8 (&bf)[2],
                                      f32x16 (&acc)[4][2]) {
  __builtin_amdgcn_s_setprio(1);
#pragma unroll
  for (int mf = 0; mf < 4; ++mf)
#pragma unroll
    for (int nf = 0; nf < 2; ++nf)
      acc[mf][nf] = __builtin_amdgcn_mfma_f32_32x32x16_f16(af[mf], bf[nf], acc[mf][nf], 0, 0, 0);
  __builtin_amdgcn_s_setprio(0);
}

__global__ __launch_bounds__(512, 2) void gemm_f16_bt(const f16* __restrict__ A,
                                                      const f16* __restrict__ B,
                                                      const float* __restrict__ bias,
                                                      float* __restrict__ C) {
  __shared__ __align__(16) char lds[163840];

  const int tid = threadIdx.x;
  const int w = tid >> 6;
  const int l = tid & 63;
  const int wr = w >> 2;  // 0..1 : 128 M-rows each
  const int wc = w & 3;   // 0..3 : 64 N-cols each

  // bijective XCD swizzle: nwg = 1376 = 8 * 172
  const int wg = blockIdx.x;
  const int swz = (wg & 7) * 172 + (wg >> 3);
  const int mt = swz / 43;
  const int nt = swz % 43;
  const int m0 = mt * 256;
  const int n0 = nt * 256;

  const char* Abase = (const char*)A + (size_t)mt * TILE_BYTES + (w << 10) + (l << 4);
  const char* Bbase = (const char*)B + (size_t)nt * TILE_BYTES + (w << 10) + (l << 4);

  char* ldsc = (char*)lds;

#define STAGE_A(dst_off, koff)                 \
  {                                            \
    char* d_ = ldsc + (dst_off) + (w << 10);   \
    gload16(Abase + (koff), d_);               \
    gload16(Abase + (koff) + 8192, d_ + 8192); \
  }
#define STAGE_B(dst_off, koff)                 \
  {                                            \
    char* d_ = ldsc + (dst_off) + (w << 10);   \
    gload16(Bbase + (koff), d_);               \
    gload16(Bbase + (koff) + 8192, d_ + 8192); \
  }

  f32x16 acc[4][2];
#pragma unroll
  for (int i = 0; i < 4; ++i)
#pragma unroll
    for (int j = 0; j < 2; ++j) acc[i][j] = (f32x16)0.f;

  const int l16 = l << 4;
  const int aF0 = wr << 13;  // (wr*8 chunks) * 1KB
  const int bF0 = wc << 12;  // (wc*4 chunks) * 1KB

  // prologue: Alo0,Ahi0,Blo0,Bhi0,Alo1,Ahi1,Blo1 = 14 gloads; vmcnt(6) confirms tile 0
  STAGE_A(0, 0);
  STAGE_A(16384, 16384);
  STAGE_B(AB_OFF, 0);
  STAGE_B(AB_OFF + 16384, 16384);
  STAGE_A(32768, 32768);
  STAGE_A(32768 + 16384, 32768 + 16384);
  STAGE_B(AB_OFF + 32768, 32768);
  asm volatile("s_waitcnt vmcnt(6)" ::: "memory");
  __builtin_amdgcn_s_barrier();

  int ap = 0;       // A parity base of tile t
  int ap2 = 65536;  // A parity base of tile t+2

  f16x8 afe[4], bfe[2];  // even-phase frags (ph0, ph2)
  f16x8 afo[4], bfo[2];  // odd-phase frags (ph1, ph3)

  // F0 of tile 0
  read_frags(ldsc, 0, AB_OFF, 0, 0, aF0, bF0, l16, afe, bfe);

  for (int t = 0; t < NT_K; ++t) {
    const int p = t & 1;
    const int pn = p ^ 1;
    const int Bb = AB_OFF + p * 32768;
    const int Bn = AB_OFF + pn * 32768;
    const int t1 = (t + 1 < NT_K) ? (t + 1) : (NT_K - 1);
    const int t2 = (t + 2 < NT_K) ? (t + 2) : (NT_K - 1);
    const int k1 = t1 * 32768;
    const int k2 = t2 * 32768;

    // ph0: consume F(0,0); read F(0,1); stage Bhi[t+1]
    read_frags(ldsc, ap, Bb, 0, 1, aF0, bF0, l16, afo, bfo);
    STAGE_B(Bn + 16384, k1 + 16384);
    mfma8(afe, bfe, acc);

    // ph1: consume F(0,1); read F(1,0); stage Alo[t+2]
    read_frags(ldsc, ap, Bb, 1, 0, aF0, bF0, l16, afe, bfe);
    STAGE_A(ap2, k2);
    mfma8(afo, bfo, acc);
    __builtin_amdgcn_s_barrier();  // mid-tile: kk0 reads all landed before Blo[t+2] DMA

    // ph2: consume F(1,0); read F(1,1); stage Ahi[t+2]
    read_frags(ldsc, ap, Bb, 1, 1, aF0, bF0, l16, afo, bfo);
    STAGE_A(ap2 + 16384, k2 + 16384);
    mfma8(afe, bfe, acc);

    // ph3: consume F(1,1); stage Blo[t+2]
    STAGE_B(Bb, k2);
    mfma8(afo, bfo, acc);
    asm volatile("s_waitcnt vmcnt(6)" ::: "memory");  // confirms tile t+1 fully in LDS
    __builtin_amdgcn_s_barrier();                     // boundary

    // advance rings; read F(0,0) of tile t+1 (safe: after boundary barrier)
    const int apN = (ap + 32768 == AB_OFF) ? 0 : ap + 32768;
    read_frags(ldsc, apN, Bn, 0, 0, aF0, bF0, l16, afe, bfe);
    ap = apN;
    ap2 = (ap2 + 32768 == AB_OFF) ? 0 : ap2 + 32768;
  }

  // epilogue: 32x32 C/D layout col = lane&31, row = (reg&3) + 8*(reg>>2) + 4*(lane>>5)
  const int l31 = l & 31;
  const int rbase = 4 * (l >> 5);
  float bv[2];
#pragma unroll
  for (int nf = 0; nf < 2; ++nf) bv[nf] = bias[n0 + wc * 64 + nf * 32 + l31];
#pragma unroll
  for (int mf = 0; mf < 4; ++mf) {
#pragma unroll
    for (int nf = 0; nf < 2; ++nf) {
      const size_t col = n0 + wc * 64 + nf * 32 + l31;
#pragma unroll
      for (int qd = 0; qd < 4; ++qd) {
#pragma unroll
        for (int j = 0; j < 4; ++j) {
          const int row = m0 + wr * 128 + mf * 32 + rbase + 8 * qd + j;
          __builtin_nontemporal_store(acc[mf][nf][qd * 4 + j] + bv[nf],
                                      &C[(size_t)row * N_DIM + col]);
        }
      }
    }
  }
#undef STAGE_A
#undef STAGE_B
}

extern "C" void kernel_launch(void* const* d_in, const int* in_sizes, int n_in,
                              void* d_out, int out_size, void* d_ws, size_t ws_size,
                              hipStream_t stream) {
  const float* x = (const float*)d_in[0];
  const int* wq = (const int*)d_in[1];
  const float* amax = (const float*)d_in[2];
  const float* bias = (const float*)d_in[3];
  float* out = (float*)d_out;

  f16* Xh = (f16*)d_ws;                                       // 64 MB, tiled
  f16* Wh = (f16*)((char*)d_ws + (size_t)M_DIM * K_DIM * 2);  // 90.25 MB, tiled

  {
    int n16x = M_DIM * K_DIM / 8;  // 4,194,304
    int n16w = N_DIM * K_DIM / 8;  // 5,636,096
    int nthr = n16x + n16w;
    prep_kernel<<<(nthr + 255) / 256, 256, 0, stream>>>(x, Xh, n16x, wq, amax, Wh, n16w);
  }
  {
    dim3 grid((M_DIM / 256) * (N_DIM / 256));  // 32*43 = 1376
    gemm_f16_bt<<<grid, 512, 0, stream>>>(Xh, Wh, bias, out);
  }
}